// Round 3
// 572.243 us; speedup vs baseline: 1.0743x; 1.0743x over previous
//
#include <hip/hip_runtime.h>
#include <hip/hip_bf16.h>

// Problem constants (B,D,H,W,C) = (2,32,56,56,96); WS=(2,7,7), SS=(1,3,3)
#define NTOK   200704      // B*D*H*W
#define NWIN   2048        // B * 1024 windows
#define NT     98          // tokens per window (2*7*7)
#define CCH    96
#define HID    384

typedef __attribute__((ext_vector_type(8))) short bf16x8;   // 8 bf16, 4 VGPRs
typedef __attribute__((ext_vector_type(4))) short s16x4;    // 4 bf16, 8 bytes
typedef __attribute__((ext_vector_type(4))) float f32x4;

__device__ __forceinline__ float bf2f(__hip_bfloat16 v) { return __bfloat162float(v); }

__device__ __forceinline__ short f2bf_s(float v) {
  __hip_bfloat16 h = __float2bfloat16(v);
  return *reinterpret_cast<short*>(&h);
}

// gelu(x) ~= x * sigmoid(1.5957691x + 0.0713548x^3)  (tanh-form GELU)
// max abs err ~2e-4 at |x|~2; fc1 activations here have sigma~0.2 -> err ~1e-5.
__device__ __forceinline__ float gelu_f(float v) {
  float u = v * (1.5957691216057308f + 0.0713548162726f * v * v);
  return __fdividef(v, 1.f + __expf(-u));
}

// ---------------- Kernel 0: convert weights to bf16 -----------------------
__global__ __launch_bounds__(256) void k0_cvt(
    const float* __restrict__ w1, const float* __restrict__ w2,
    const float* __restrict__ qkvw, const float* __restrict__ pw,
    __hip_bfloat16* __restrict__ w1b, __hip_bfloat16* __restrict__ w2b,
    __hip_bfloat16* __restrict__ qkvwb, __hip_bfloat16* __restrict__ pwb) {
  int i = blockIdx.x * 256 + threadIdx.x;
  if (i < HID * CCH) {
    w1b[i] = __float2bfloat16(w1[i]);
    w2b[i] = __float2bfloat16(w2[i]);
  }
  if (i < 3 * CCH * CCH) qkvwb[i] = __float2bfloat16(qkvw[i]);
  if (i < CCH * CCH)     pwb[i]   = __float2bfloat16(pw[i]);
}

// ---------------- Kernel 1: LN1 + shift + window partition -> xw (bf16) ----
__global__ __launch_bounds__(256) void k1_ln_window(
    const float* __restrict__ x, const float* __restrict__ g,
    const float* __restrict__ bt, __hip_bfloat16* __restrict__ xw) {
  int token = blockIdx.x * 8 + (threadIdx.x >> 5);
  int lane = threadIdx.x & 31;
  if (token >= NTOK) return;
  int wb = token / NT;
  int n  = token - wb * NT;
  int b = wb >> 10;
  int rem = wb & 1023;
  int wd = rem >> 6, wh = (rem >> 3) & 7, ww = rem & 7;
  int id = n / 49, ih = (n / 7) % 7, iw = n % 7;
  int dd = wd * 2 + id + 1; if (dd >= 32) dd -= 32;
  int hh = wh * 7 + ih + 3; if (hh >= 56) hh -= 56;
  int w2 = ww * 7 + iw + 3; if (w2 >= 56) w2 -= 56;
  const float* src = x + ((((size_t)b * 32 + dd) * 56 + hh) * 56 + w2) * CCH;
  float v0 = src[lane], v1 = src[lane + 32], v2 = src[lane + 64];
  float s = v0 + v1 + v2, ss = v0 * v0 + v1 * v1 + v2 * v2;
  #pragma unroll
  for (int off = 16; off; off >>= 1) {
    s  += __shfl_xor(s,  off, 32);
    ss += __shfl_xor(ss, off, 32);
  }
  float m   = s * (1.f / 96.f);
  float inv = rsqrtf(ss * (1.f / 96.f) - m * m + 1e-5f);
  __hip_bfloat16* dst = xw + (size_t)token * CCH;
  dst[lane]      = __float2bfloat16((v0 - m) * inv * g[lane]      + bt[lane]);
  dst[lane + 32] = __float2bfloat16((v1 - m) * inv * g[lane + 32] + bt[lane + 32]);
  dst[lane + 64] = __float2bfloat16((v2 - m) * inv * g[lane + 64] + bt[lane + 64]);
}

// ---------------- Kernel 2: per-(window,head) MFMA attention --------------
// Flat grid: bid -> (win = bid/3, head = bid%3) so the 3 head-blocks of a
// window are dispatch-adjacent (xw window stays L2-resident).
// LDS 46.8 KB -> 3 blocks/CU. PV = 3 MFMA (K=96) + fp32 rank-2 tail for
// tokens 96/97 (P tail from softmax regs via shfl, V tail via scalar LDS).
// A-frag: elem j of lane l = M[l&15][(l>>4)*8+j]; B-frag: B[(l>>4)*8+j][l&15];
// C/D: col=l&15, row=(l>>4)*4+reg.
#define XS_S 104    // X row stride (bf16); also P stride (cols 0..95 used)
#define QK_S 40     // Q/K row stride
#define VT_S 104    // V^T row stride (cols = tokens 0..97 used)
__global__ __launch_bounds__(256) void k2_attn(
    const __hip_bfloat16* __restrict__ xw, const __hip_bfloat16* __restrict__ qkvwb,
    const float* __restrict__ qkv_b, const float* __restrict__ mask,
    __hip_bfloat16* __restrict__ obuf) {
  __shared__ __align__(16) __hip_bfloat16 U1[112 * XS_S];  // Xs then P
  __shared__ __align__(16) __hip_bfloat16 Qs[112 * QK_S];
  __shared__ __align__(16) __hip_bfloat16 Ks[112 * QK_S];
  __shared__ __align__(16) __hip_bfloat16 Vts[32 * VT_S];
  int bid = blockIdx.x, tid = threadIdx.x;
  int wb = bid / 3, h = bid - wb * 3;
  int wid = tid >> 6, lane = tid & 63, lr = lane & 15, lq = lane >> 4;
  int mw = wb & 1023;
  int wd = mw >> 6, wh = (mw >> 3) & 7, ww = mw & 7;
  bool hasmask = (wd == 15) || (wh == 7) || (ww == 7);
  const __hip_bfloat16* xp = xw + (size_t)wb * (NT * CCH);
  const float* mbase = mask + (size_t)mw * (NT * NT);

  // stage Xs (zero pad rows 98..111)
  for (int q = tid; q < 112 * 12; q += 256) {
    int n = q / 12, g = q - n * 12;
    bf16x8 v = {0, 0, 0, 0, 0, 0, 0, 0};
    if (n < NT) v = *(const bf16x8*)(xp + n * CCH + g * 8);
    *(bf16x8*)&U1[n * XS_S + g * 8] = v;
  }
  __syncthreads();

  // qkv for head h: 7 mt x 6 ct tiles, K=96
  for (int job = wid; job < 42; job += 4) {
    int mt = job / 6, ct = job - (job / 6) * 6;
    int which = ct >> 1;                       // 0=Q,1=K,2=V
    int grow = which * CCH + h * 32 + (ct & 1) * 16 + lr;
    float bv = qkv_b[grow];
    f32x4 acc = {bv, bv, bv, bv};
    const __hip_bfloat16* wrow = qkvwb + (size_t)grow * CCH;
    #pragma unroll
    for (int ks = 0; ks < 3; ++ks) {
      bf16x8 a = *(const bf16x8*)&U1[(mt * 16 + lr) * XS_S + ks * 32 + lq * 8];
      bf16x8 b = *(const bf16x8*)(wrow + ks * 32 + lq * 8);
      acc = __builtin_amdgcn_mfma_f32_16x16x32_bf16(a, b, acc, 0, 0, 0);
    }
    int d = (ct & 1) * 16 + lr;
    #pragma unroll
    for (int r = 0; r < 4; ++r) {
      int token = mt * 16 + lq * 4 + r;
      if (which == 0)
        Qs[token * QK_S + d] = __float2bfloat16(acc[r] * 0.17677669529663689f);
      else if (which == 1)
        Ks[token * QK_S + d] = __float2bfloat16(acc[r]);
      else if (token < NT)
        Vts[d * VT_S + token] = __float2bfloat16(acc[r]);
    }
  }
  __syncthreads();   // Xs dead from here; U1 becomes P (cols 0..95)

  __hip_bfloat16* Pp = U1;   // [112][104], cols 0..95 used by PV MFMA
  for (int mt = wid; mt < 7; mt += 4) {
    // QK^T: one MFMA per N-tile (K = head dim = 32)
    f32x4 s[7];
    #pragma unroll
    for (int nt = 0; nt < 7; ++nt) s[nt] = {0.f, 0.f, 0.f, 0.f};
    bf16x8 aq = *(const bf16x8*)&Qs[(mt * 16 + lr) * QK_S + lq * 8];
    #pragma unroll
    for (int nt = 0; nt < 7; ++nt) {
      bf16x8 bk = *(const bf16x8*)&Ks[(nt * 16 + lr) * QK_S + lq * 8];
      s[nt] = __builtin_amdgcn_mfma_f32_16x16x32_bf16(aq, bk, s[nt], 0, 0, 0);
    }
    // mask + column bounds
    #pragma unroll
    for (int nt = 0; nt < 7; ++nt) {
      int j = nt * 16 + lr;
      if (j >= NT) {
        s[nt] = {-1e30f, -1e30f, -1e30f, -1e30f};
      } else if (hasmask) {
        #pragma unroll
        for (int r = 0; r < 4; ++r) {
          int i = mt * 16 + lq * 4 + r;
          if (i < NT) s[nt][r] += mbase[i * NT + j];
        }
      }
    }
    // softmax per row (row = (lq, r); spread over 16 lanes x 7 regs)
    #pragma unroll
    for (int r = 0; r < 4; ++r) {
      float m = s[0][r];
      #pragma unroll
      for (int nt = 1; nt < 7; ++nt) m = fmaxf(m, s[nt][r]);
      #pragma unroll
      for (int off = 1; off < 16; off <<= 1) m = fmaxf(m, __shfl_xor(m, off));
      float sum = 0.f;
      #pragma unroll
      for (int nt = 0; nt < 7; ++nt) {
        float e = __expf(s[nt][r] - m);
        s[nt][r] = e;
        sum += e;
      }
      #pragma unroll
      for (int off = 1; off < 16; off <<= 1) sum += __shfl_xor(sum, off);
      float inv = 1.f / sum;
      #pragma unroll
      for (int nt = 0; nt < 7; ++nt) s[nt][r] *= inv;
      // write P cols 0..95 (nt 0..5); nt=6 (tokens 96/97) stays in regs
      #pragma unroll
      for (int nt = 0; nt < 6; ++nt)
        Pp[(mt * 16 + lq * 4 + r) * XS_S + nt * 16 + lr] =
            __float2bfloat16(s[nt][r]);
    }
    // PV: O[16 x 32] = P[16 x 96] * V[96 x 32] + rank-2 tail (tokens 96,97)
    bf16x8 ap[3];
    #pragma unroll
    for (int ks = 0; ks < 3; ++ks)
      ap[ks] = *(const bf16x8*)&Pp[(mt * 16 + lr) * XS_S + ks * 32 + lq * 8];
    #pragma unroll
    for (int nt2 = 0; nt2 < 2; ++nt2) {
      f32x4 ao = {0.f, 0.f, 0.f, 0.f};
      #pragma unroll
      for (int ks = 0; ks < 3; ++ks) {
        bf16x8 bv = *(const bf16x8*)&Vts[(nt2 * 16 + lr) * VT_S + ks * 32 + lq * 8];
        ao = __builtin_amdgcn_mfma_f32_16x16x32_bf16(ap[ks], bv, ao, 0, 0, 0);
      }
      float v96 = bf2f(Vts[(nt2 * 16 + lr) * VT_S + 96]);
      float v97 = bf2f(Vts[(nt2 * 16 + lr) * VT_S + 97]);
      #pragma unroll
      for (int r = 0; r < 4; ++r) {
        float p96 = __shfl(s[6][r], lane & 48);        // P[row][96] from lane lq*16+0
        float p97 = __shfl(s[6][r], (lane & 48) | 1);  // P[row][97] from lane lq*16+1
        ao[r] += p96 * v96 + p97 * v97;
        int token = mt * 16 + lq * 4 + r;
        if (token < NT)
          obuf[((size_t)wb * NT + token) * CCH + h * 32 + nt2 * 16 + lr] =
              __float2bfloat16(ao[r]);
      }
    }
  }
}

// ---------------- Kernel 3: MFMA proj + window-reverse + residual ---------
__global__ __launch_bounds__(256) void k3_proj(
    const __hip_bfloat16* __restrict__ obuf, const float* __restrict__ x,
    const __hip_bfloat16* __restrict__ pwb, const float* __restrict__ pb,
    float* __restrict__ out) {
  __shared__ __align__(16) __hip_bfloat16 os[112 * XS_S];
  int wb = blockIdx.x, tid = threadIdx.x;
  int wid = tid >> 6, lane = tid & 63, lr = lane & 15, lq = lane >> 4;
  const __hip_bfloat16* src = obuf + (size_t)wb * (NT * CCH);
  for (int q = tid; q < 112 * 12; q += 256) {
    int n = q / 12, g = q - n * 12;
    bf16x8 v = {0, 0, 0, 0, 0, 0, 0, 0};
    if (n < NT) v = *(const bf16x8*)(src + n * CCH + g * 8);
    *(bf16x8*)&os[n * XS_S + g * 8] = v;
  }
  __syncthreads();
  int b = wb >> 10, rem = wb & 1023;
  int wd = rem >> 6, wh = (rem >> 3) & 7, ww = rem & 7;
  for (int job = wid; job < 42; job += 4) {
    int mt = job / 6, ct = job - (job / 6) * 6;
    float bv = pb[ct * 16 + lr];
    f32x4 acc = {bv, bv, bv, bv};
    const __hip_bfloat16* wrow = pwb + (size_t)(ct * 16 + lr) * CCH;
    #pragma unroll
    for (int ks = 0; ks < 3; ++ks) {
      bf16x8 a = *(const bf16x8*)&os[(mt * 16 + lr) * XS_S + ks * 32 + lq * 8];
      bf16x8 bw = *(const bf16x8*)(wrow + ks * 32 + lq * 8);
      acc = __builtin_amdgcn_mfma_f32_16x16x32_bf16(a, bw, acc, 0, 0, 0);
    }
    #pragma unroll
    for (int r = 0; r < 4; ++r) {
      int token = mt * 16 + lq * 4 + r;
      if (token < NT) {
        int id = token / 49, r2 = token - id * 49;
        int ih = r2 / 7, iw = r2 - ih * 7;
        int dd = wd * 2 + id + 1; if (dd >= 32) dd -= 32;
        int hh = wh * 7 + ih + 3; if (hh >= 56) hh -= 56;
        int w2 = ww * 7 + iw + 3; if (w2 >= 56) w2 -= 56;
        size_t gi = ((((size_t)b * 32 + dd) * 56 + hh) * 56 + w2) * CCH + ct * 16 + lr;
        out[gi] = x[gi] + acc[r];
      }
    }
  }
}

// ---------------- Kernel 4: MFMA MLP: LN2 + fc1 + GELU + fc2 + residual ---
// 32 tokens/block, LDS = Xb 6.5KB + Ht 24KB = 31.2KB -> 5 blocks/CU (62%).
// fc1 computed TRANSPOSED (Ht = W1 * X^T, operand-swapped MFMA) so each lane
// holds 4 consecutive hid values of one token -> packed ds_write_b64 into a
// XOR-swizzled [32][384] bf16 Ht; fc2 reads A-frags back as ds_read_b128
// with the same swizzle. GELU via tanh-form sigmoid approx (no erff).
#define XB_S 104
__global__ __launch_bounds__(256, 5) void k4_mlp(
    float* __restrict__ io, const float* __restrict__ g, const float* __restrict__ bt,
    const __hip_bfloat16* __restrict__ w1b, const float* __restrict__ b1,
    const __hip_bfloat16* __restrict__ w2b, const float* __restrict__ b2) {
  __shared__ __align__(16) __hip_bfloat16 Xb[32 * XB_S];   // 6656 B
  __shared__ __align__(16) __hip_bfloat16 Ht[32 * 384];    // 24576 B, swizzled
  int tid = threadIdx.x;
  size_t base = (size_t)blockIdx.x * 32 * CCH;
  {
    int grp = tid >> 5, lane = tid & 31;
    #pragma unroll
    for (int t0 = 0; t0 < 4; ++t0) {
      int t = grp + t0 * 8;
      const float* src = io + base + (size_t)t * CCH;
      float v0 = src[lane], v1 = src[lane + 32], v2 = src[lane + 64];
      float s = v0 + v1 + v2, ss = v0 * v0 + v1 * v1 + v2 * v2;
      #pragma unroll
      for (int off = 16; off; off >>= 1) {
        s  += __shfl_xor(s,  off, 32);
        ss += __shfl_xor(ss, off, 32);
      }
      float m   = s * (1.f / 96.f);
      float inv = rsqrtf(ss * (1.f / 96.f) - m * m + 1e-5f);
      Xb[t * XB_S + lane]      = __float2bfloat16((v0 - m) * inv * g[lane]      + bt[lane]);
      Xb[t * XB_S + lane + 32] = __float2bfloat16((v1 - m) * inv * g[lane + 32] + bt[lane + 32]);
      Xb[t * XB_S + lane + 64] = __float2bfloat16((v2 - m) * inv * g[lane + 64] + bt[lane + 64]);
    }
  }
  __syncthreads();
  int wid = tid >> 6, lane = tid & 63, lr = lane & 15, lq = lane >> 4;
  // ---- fc1' : Ht tile D = W1_tile(16 hid x 32 C) * X^T_tile(32 C x 16 tok)
  // a-frag = W1[16*nt'+lr][k], b-frag = X[token=lr][k] (same bytes as the
  // usual A-frag of X) -> acc[r] = H[token=lr][hid = blk + 4*lq + r].
  {
    bf16x8 xb[2][3];
    #pragma unroll
    for (int tt = 0; tt < 2; ++tt)
      #pragma unroll
      for (int ks = 0; ks < 3; ++ks)
        xb[tt][ks] = *(const bf16x8*)&Xb[(tt * 16 + lr) * XB_S + ks * 32 + lq * 8];
    f32x4 acc[2][6];
    #pragma unroll
    for (int nt = 0; nt < 6; ++nt) {
      f32x4 bv = *(const f32x4*)&b1[96 * wid + 16 * nt + 4 * lq];
      acc[0][nt] = bv;
      acc[1][nt] = bv;
    }
    const __hip_bfloat16* wrow = w1b + (size_t)(96 * wid + lr) * CCH;
    #pragma unroll
    for (int nt = 0; nt < 6; ++nt) {
      #pragma unroll
      for (int ks = 0; ks < 3; ++ks) {
        bf16x8 a = *(const bf16x8*)(wrow + (size_t)(16 * nt) * CCH + ks * 32 + lq * 8);
        acc[0][nt] = __builtin_amdgcn_mfma_f32_16x16x32_bf16(a, xb[0][ks], acc[0][nt], 0, 0, 0);
        acc[1][nt] = __builtin_amdgcn_mfma_f32_16x16x32_bf16(a, xb[1][ks], acc[1][nt], 0, 0, 0);
      }
    }
    // GELU + pack 4 bf16 -> one 8B swizzled store per tile
    #pragma unroll
    for (int tt = 0; tt < 2; ++tt) {
      int row = tt * 16 + lr;
      char* hb = (char*)Ht + row * 768;
      int sw = (row & 7) << 4;
      #pragma unroll
      for (int nt = 0; nt < 6; ++nt) {
        s16x4 pk;
        #pragma unroll
        for (int r = 0; r < 4; ++r) pk[r] = f2bf_s(gelu_f(acc[tt][nt][r]));
        *(s16x4*)(hb + ((192 * wid + 32 * nt + 8 * lq) ^ sw)) = pk;
      }
    }
  }
  __syncthreads();
  // ---- fc2: O[32 x 96] = H[32 x 384] * W2^T + residual
  {
    int tt = wid >> 1, ntb = (wid & 1) * 3;
    f32x4 acc2[3];
    #pragma unroll
    for (int j = 0; j < 3; ++j) {
      float bv = b2[16 * (ntb + j) + lr];
      acc2[j] = {bv, bv, bv, bv};
    }
    const char* hb = (const char*)Ht + (tt * 16 + lr) * 768;
    int sw = (lr & 7) << 4;
    #pragma unroll 4
    for (int kk = 0; kk < 12; ++kk) {
      bf16x8 a = *(const bf16x8*)(hb + ((64 * kk + 16 * lq) ^ sw));
      #pragma unroll
      for (int j = 0; j < 3; ++j) {
        bf16x8 b = *(const bf16x8*)&w2b[(size_t)(16 * (ntb + j) + lr) * HID + kk * 32 + lq * 8];
        acc2[j] = __builtin_amdgcn_mfma_f32_16x16x32_bf16(a, b, acc2[j], 0, 0, 0);
      }
    }
    #pragma unroll
    for (int j = 0; j < 3; ++j)
      #pragma unroll
      for (int r = 0; r < 4; ++r) {
        size_t gi = base + (size_t)(tt * 16 + lq * 4 + r) * CCH + 16 * (ntb + j) + lr;
        io[gi] = io[gi] + acc2[j][r];
      }
  }
}

extern "C" void kernel_launch(void* const* d_in, const int* in_sizes, int n_in,
                              void* d_out, int out_size, void* d_ws, size_t ws_size,
                              hipStream_t stream) {
  const float* x    = (const float*)d_in[0];
  const float* mask = (const float*)d_in[1];
  const float* n1g  = (const float*)d_in[2];
  const float* n1b  = (const float*)d_in[3];
  const float* qkvw = (const float*)d_in[4];
  const float* qkvb = (const float*)d_in[5];
  const float* pw   = (const float*)d_in[6];
  const float* pb   = (const float*)d_in[7];
  const float* n2g  = (const float*)d_in[8];
  const float* n2b  = (const float*)d_in[9];
  const float* w1   = (const float*)d_in[10];
  const float* b1   = (const float*)d_in[11];
  const float* w2   = (const float*)d_in[12];
  const float* b2   = (const float*)d_in[13];
  float* out = (float*)d_out;

  __hip_bfloat16* xw    = (__hip_bfloat16*)d_ws;
  __hip_bfloat16* obuf  = xw + (size_t)NTOK * CCH;
  __hip_bfloat16* w1b   = obuf + (size_t)NTOK * CCH;
  __hip_bfloat16* w2b   = w1b + HID * CCH;
  __hip_bfloat16* qkvwb = w2b + HID * CCH;
  __hip_bfloat16* pwb   = qkvwb + 3 * CCH * CCH;

  k0_cvt<<<(HID * CCH + 255) / 256, 256, 0, stream>>>(w1, w2, qkvw, pw, w1b, w2b, qkvwb, pwb);
  k1_ln_window<<<NTOK / 8, 256, 0, stream>>>(x, n1g, n1b, xw);
  k2_attn<<<NWIN * 3, 256, 0, stream>>>(xw, qkvwb, qkvb, mask, obuf);
  k3_proj<<<NWIN, 256, 0, stream>>>(obuf, x, pwb, pb, out);
  k4_mlp<<<NTOK / 32, 256, 0, stream>>>(out, n2g, n2b, w1b, b1, w2b, b2);
}

// Round 5
// 482.246 us; speedup vs baseline: 1.2748x; 1.1866x over previous
//
#include <hip/hip_runtime.h>
#include <hip/hip_bf16.h>

// Problem constants (B,D,H,W,C) = (2,32,56,56,96); WS=(2,7,7), SS=(1,3,3)
#define NTOK   200704      // B*D*H*W
#define NWIN   2048        // B * 1024 windows
#define NT     98          // tokens per window (2*7*7)
#define CCH    96
#define HID    384

typedef __attribute__((ext_vector_type(8))) short bf16x8;   // 8 bf16, 4 VGPRs
typedef __attribute__((ext_vector_type(4))) short s16x4;    // 4 bf16, 8 bytes
typedef __attribute__((ext_vector_type(4))) float f32x4;
typedef __attribute__((ext_vector_type(4))) int   i32x4;

#define MFMA(a, b, c) __builtin_amdgcn_mfma_f32_16x16x32_bf16((a), (b), (c), 0, 0, 0)

__device__ __forceinline__ float bf2f(__hip_bfloat16 v) { return __bfloat162float(v); }

__device__ __forceinline__ short f2bf_s(float v) {
  __hip_bfloat16 h = __float2bfloat16(v);
  return *reinterpret_cast<short*>(&h);
}

__device__ __forceinline__ unsigned pack2(float a, float b) {
  unsigned ua = (unsigned short)f2bf_s(a);
  unsigned ub = (unsigned short)f2bf_s(b);
  return ua | (ub << 16);
}

// gelu(x) ~= x * sigmoid(1.5957691x + 0.0713548x^3)  (tanh-form GELU)
__device__ __forceinline__ float gelu_f(float v) {
  float u = v * (1.5957691216057308f + 0.0713548162726f * v * v);
  return __fdividef(v, 1.f + __expf(-u));
}

// ---------------- Kernel 0: convert weights to bf16 -----------------------
__global__ __launch_bounds__(256) void k0_cvt(
    const float* __restrict__ w1, const float* __restrict__ w2,
    const float* __restrict__ qkvw, const float* __restrict__ pw,
    __hip_bfloat16* __restrict__ w1b, __hip_bfloat16* __restrict__ w2b,
    __hip_bfloat16* __restrict__ qkvwb, __hip_bfloat16* __restrict__ pwb) {
  int i = blockIdx.x * 256 + threadIdx.x;
  if (i < HID * CCH) {
    w1b[i] = __float2bfloat16(w1[i]);
    w2b[i] = __float2bfloat16(w2[i]);
  }
  if (i < 3 * CCH * CCH) qkvwb[i] = __float2bfloat16(qkvw[i]);
  if (i < CCH * CCH)     pwb[i]   = __float2bfloat16(pw[i]);
}

// ---------------- Kernel 1: LN1 + shift + window partition -> xw (bf16) ----
__global__ __launch_bounds__(256) void k1_ln_window(
    const float* __restrict__ x, const float* __restrict__ g,
    const float* __restrict__ bt, __hip_bfloat16* __restrict__ xw) {
  int token = blockIdx.x * 8 + (threadIdx.x >> 5);
  int lane = threadIdx.x & 31;
  if (token >= NTOK) return;
  int wb = token / NT;
  int n  = token - wb * NT;
  int b = wb >> 10;
  int rem = wb & 1023;
  int wd = rem >> 6, wh = (rem >> 3) & 7, ww = rem & 7;
  int id = n / 49, ih = (n / 7) % 7, iw = n % 7;
  int dd = wd * 2 + id + 1; if (dd >= 32) dd -= 32;
  int hh = wh * 7 + ih + 3; if (hh >= 56) hh -= 56;
  int w2 = ww * 7 + iw + 3; if (w2 >= 56) w2 -= 56;
  const float* src = x + ((((size_t)b * 32 + dd) * 56 + hh) * 56 + w2) * CCH;
  float v0 = src[lane], v1 = src[lane + 32], v2 = src[lane + 64];
  float s = v0 + v1 + v2, ss = v0 * v0 + v1 * v1 + v2 * v2;
  #pragma unroll
  for (int off = 16; off; off >>= 1) {
    s  += __shfl_xor(s,  off, 32);
    ss += __shfl_xor(ss, off, 32);
  }
  float m   = s * (1.f / 96.f);
  float inv = rsqrtf(ss * (1.f / 96.f) - m * m + 1e-5f);
  __hip_bfloat16* dst = xw + (size_t)token * CCH;
  dst[lane]      = __float2bfloat16((v0 - m) * inv * g[lane]      + bt[lane]);
  dst[lane + 32] = __float2bfloat16((v1 - m) * inv * g[lane + 32] + bt[lane + 32]);
  dst[lane + 64] = __float2bfloat16((v2 - m) * inv * g[lane + 64] + bt[lane + 64]);
}

// ---------------- Kernel 2: per-(window,head) MFMA attention --------------
// Rewritten: no Xs staging (QKV A/B frags straight from global; window is
// L1/L2-resident), operand-swapped QKV/QK^T/PV so softmax is per-lane
// (query in lane), P stays in registers (shfl-built P^T b-frags), all LDS
// writes packed b64. Mask from arithmetic region ids (mask matrix is
// symmetric; ids depend only on window coords). LDS 25.7KB, 1 barrier.
// Layouts: A-frag elem j lane l = M[l&15][(l>>4)*8+j];
//          B-frag elem j lane l = B[(l>>4)*8+j][l&15];
//          C/D: col=l&15, row=(l>>4)*4+reg.
#define QK_S 40     // Q/K row stride (elems)
#define VT_S 120    // V^T row stride (elems); cols 0..111 used
__global__ __launch_bounds__(256, 4) void k2_attn(
    const __hip_bfloat16* __restrict__ xw, const __hip_bfloat16* __restrict__ qkvwb,
    const float* __restrict__ qkv_b, __hip_bfloat16* __restrict__ obuf) {
  __shared__ __align__(16) __hip_bfloat16 Qs[112 * QK_S];   // [token][dim]
  __shared__ __align__(16) __hip_bfloat16 Ks[112 * QK_S];   // [token][dim]
  __shared__ __align__(16) __hip_bfloat16 Vts[32 * VT_S];   // [dim][token]
  __shared__ unsigned char ridL[112];
  int bid = blockIdx.x, tid = threadIdx.x;
  int wb = bid / 3, h = bid - wb * 3;
  int wid = tid >> 6, lane = tid & 63, lr = lane & 15, lq = lane >> 4;
  int mw = wb & 1023;
  int wd = mw >> 6, wh = (mw >> 3) & 7, ww = mw & 7;
  bool hasmask = (wd == 15) || (wh == 7) || (ww == 7);
  const __hip_bfloat16* xp = xw + (size_t)wb * (NT * CCH);
  int h32 = h * 32;

  // region ids (reproduces mask_matrix: -100 iff region ids differ; symmetric)
  if (tid < 112) {
    int n = tid < NT ? tid : NT - 1;
    int id = n / 49, r2 = n - id * 49, ih = r2 / 7, iw = r2 - ih * 7;
    int ud = wd * 2 + id, uh = wh * 7 + ih, uw = ww * 7 + iw;
    int dr = (ud < 30) ? 0 : (ud == 30 ? 1 : 2);
    int hr = (uh < 49) ? 0 : (uh < 53 ? 1 : 2);
    int wr = (uw < 49) ? 0 : (uw < 53 ? 1 : 2);
    ridL[tid] = (unsigned char)(dr * 9 + hr * 3 + wr);
  }

  // ---- QKV: 7 token-tiles x 6 out-tiles (Q0,Q1,K0,K1,V0,V1), K=96 ----
  for (int job = wid; job < 42; job += 4) {
    int mt = job / 6, ct = job - (job / 6) * 6;
    int tok = mt * 16 + lr;
    int tokc = tok < NT ? tok : NT - 1;       // clamp: rows >=98 duplicate 97
    const __hip_bfloat16* xrow = xp + (size_t)tokc * CCH;
    bf16x8 xf0 = *(const bf16x8*)(xrow + lq * 8);
    bf16x8 xf1 = *(const bf16x8*)(xrow + 32 + lq * 8);
    bf16x8 xf2 = *(const bf16x8*)(xrow + 64 + lq * 8);
    if (ct < 4) {
      // swapped: D = W * X^T -> lane holds token=lr, dims lq*4+r
      int which = ct >> 1;                    // 0=Q, 1=K
      int grow0 = which * CCH + h32 + (ct & 1) * 16;
      const __hip_bfloat16* wr0 = qkvwb + (size_t)(grow0 + lr) * CCH;
      f32x4 acc = *(const f32x4*)&qkv_b[grow0 + lq * 4];
      acc = MFMA(*(const bf16x8*)(wr0 + lq * 8),      xf0, acc);
      acc = MFMA(*(const bf16x8*)(wr0 + 32 + lq * 8), xf1, acc);
      acc = MFMA(*(const bf16x8*)(wr0 + 64 + lq * 8), xf2, acc);
      if (which == 0) {
        #pragma unroll
        for (int r = 0; r < 4; ++r) acc[r] *= 0.17677669529663689f;
      }
      s16x4 pk4;
      #pragma unroll
      for (int r = 0; r < 4; ++r) pk4[r] = f2bf_s(acc[r]);
      __hip_bfloat16* dst = (which == 0) ? Qs : Ks;
      *(s16x4*)&dst[tok * QK_S + (ct & 1) * 16 + lq * 4] = pk4;
    } else {
      // plain: D = X * W^T -> lane holds dim=lr, tokens lq*4+r -> V^T rows
      int dt = ct & 1;
      int vrow = 2 * CCH + h32 + dt * 16 + lr;
      const __hip_bfloat16* wv = qkvwb + (size_t)vrow * CCH;
      float bv = qkv_b[vrow];
      f32x4 acc = {bv, bv, bv, bv};
      acc = MFMA(xf0, *(const bf16x8*)(wv + lq * 8),      acc);
      acc = MFMA(xf1, *(const bf16x8*)(wv + 32 + lq * 8), acc);
      acc = MFMA(xf2, *(const bf16x8*)(wv + 64 + lq * 8), acc);
      s16x4 pk4;
      #pragma unroll
      for (int r = 0; r < 4; ++r) pk4[r] = f2bf_s(acc[r]);
      *(s16x4*)&Vts[(dt * 16 + lr) * VT_S + mt * 16 + lq * 4] = pk4;
    }
  }
  __syncthreads();

  // ---- attention: S^T = K*Q^T; softmax per lane (query=lr); O^T = V^T*P^T
  for (int mt = wid; mt < 7; mt += 4) {
    bf16x8 qf = *(const bf16x8*)&Qs[(mt * 16 + lr) * QK_S + lq * 8];
    f32x4 s[7];
    #pragma unroll
    for (int nt = 0; nt < 7; ++nt) s[nt] = {0.f, 0.f, 0.f, 0.f};
    #pragma unroll
    for (int nt = 0; nt < 7; ++nt) {
      bf16x8 kf = *(const bf16x8*)&Ks[(nt * 16 + lr) * QK_S + lq * 8];
      s[nt] = MFMA(kf, qf, s[nt]);   // lane: key = nt*16+lq*4+r, query = mt*16+lr
    }
    if (hasmask) {
      int rq = ridL[mt * 16 + lr];
      #pragma unroll
      for (int nt = 0; nt < 7; ++nt)
        #pragma unroll
        for (int r = 0; r < 4; ++r)
          s[nt][r] += (ridL[nt * 16 + lq * 4 + r] != rq) ? -100.f : 0.f;
    }
    #pragma unroll
    for (int r = 0; r < 4; ++r)   // kill keys 98..111
      s[6][r] = (lq * 4 + r >= 2) ? -1e30f : s[6][r];
    // softmax over this lane's 28 keys + cross-lq reduce (lanes 16/32 apart)
    float m = s[0][0];
    #pragma unroll
    for (int nt = 0; nt < 7; ++nt)
      #pragma unroll
      for (int r = 0; r < 4; ++r) m = fmaxf(m, s[nt][r]);
    m = fmaxf(m, __shfl_xor(m, 16));
    m = fmaxf(m, __shfl_xor(m, 32));
    float sum = 0.f;
    #pragma unroll
    for (int nt = 0; nt < 7; ++nt)
      #pragma unroll
      for (int r = 0; r < 4; ++r) {
        float e = __expf(s[nt][r] - m);
        s[nt][r] = e;
        sum += e;
      }
    sum += __shfl_xor(sum, 16);
    sum += __shfl_xor(sum, 32);
    float inv = 1.f / sum;
    #pragma unroll
    for (int nt = 0; nt < 7; ++nt)
      #pragma unroll
      for (int r = 0; r < 4; ++r) s[nt][r] *= inv;
    // pack P (keys 0..95) as bf16 pairs; s[6] kept f32 for the tail
    unsigned pk[6][2];
    #pragma unroll
    for (int nt = 0; nt < 6; ++nt) {
      pk[nt][0] = pack2(s[nt][0], s[nt][1]);
      pk[nt][1] = pack2(s[nt][2], s[nt][3]);
    }
    // PV: build P^T b-frags via shfl (elem j lane l = P[q=lr][ks*32+lq*8+j])
    f32x4 o0 = {0.f, 0.f, 0.f, 0.f}, o1 = {0.f, 0.f, 0.f, 0.f};
    int srcA = lr + ((lq & 1) << 5);
    bool hi = (lq & 2) != 0;
    #pragma unroll
    for (int ks = 0; ks < 3; ++ks) {
      int a0 = __shfl((int)pk[2 * ks][0], srcA);
      int b0 = __shfl((int)pk[2 * ks + 1][0], srcA);
      int a1 = __shfl((int)pk[2 * ks][1], srcA);
      int b1 = __shfl((int)pk[2 * ks + 1][1], srcA);
      int a2 = __shfl((int)pk[2 * ks][0], srcA + 16);
      int b2 = __shfl((int)pk[2 * ks + 1][0], srcA + 16);
      int a3 = __shfl((int)pk[2 * ks][1], srcA + 16);
      int b3 = __shfl((int)pk[2 * ks + 1][1], srcA + 16);
      i32x4 wv4;
      wv4[0] = hi ? b0 : a0;
      wv4[1] = hi ? b1 : a1;
      wv4[2] = hi ? b2 : a2;
      wv4[3] = hi ? b3 : a3;
      bf16x8 pf = __builtin_bit_cast(bf16x8, wv4);
      o0 = MFMA(*(const bf16x8*)&Vts[lr * VT_S + ks * 32 + lq * 8], pf, o0);
      o1 = MFMA(*(const bf16x8*)&Vts[(16 + lr) * VT_S + ks * 32 + lq * 8], pf, o1);
    }
    // rank-2 tail: keys 96, 97 (P from lq=0 lanes' s[6][0..1])
    float p96 = __shfl(s[6][0], lr);
    float p97 = __shfl(s[6][1], lr);
    #pragma unroll
    for (int r = 0; r < 4; ++r) {
      int d0 = lq * 4 + r, d1 = 16 + lq * 4 + r;
      o0[r] += p96 * bf2f(Vts[d0 * VT_S + 96]) + p97 * bf2f(Vts[d0 * VT_S + 97]);
      o1[r] += p96 * bf2f(Vts[d1 * VT_S + 96]) + p97 * bf2f(Vts[d1 * VT_S + 97]);
    }
    int q = mt * 16 + lr;
    if (q < NT) {     // lane: O^T[d = dt*16+lq*4+r][q] -> packed 8B stores
      __hip_bfloat16* ob = obuf + ((size_t)wb * NT + q) * CCH + h32;
      s16x4 w0, w1;
      #pragma unroll
      for (int r = 0; r < 4; ++r) { w0[r] = f2bf_s(o0[r]); w1[r] = f2bf_s(o1[r]); }
      *(s16x4*)(ob + lq * 4) = w0;
      *(s16x4*)(ob + 16 + lq * 4) = w1;
    }
  }
}

// ---------------- Kernel 3: MFMA proj + window-reverse + residual ---------
#define XS_S 104
__global__ __launch_bounds__(256) void k3_proj(
    const __hip_bfloat16* __restrict__ obuf, const float* __restrict__ x,
    const __hip_bfloat16* __restrict__ pwb, const float* __restrict__ pb,
    float* __restrict__ out) {
  __shared__ __align__(16) __hip_bfloat16 os[112 * XS_S];
  int wb = blockIdx.x, tid = threadIdx.x;
  int wid = tid >> 6, lane = tid & 63, lr = lane & 15, lq = lane >> 4;
  const __hip_bfloat16* src = obuf + (size_t)wb * (NT * CCH);
  for (int q = tid; q < 112 * 12; q += 256) {
    int n = q / 12, g = q - n * 12;
    bf16x8 v = {0, 0, 0, 0, 0, 0, 0, 0};
    if (n < NT) v = *(const bf16x8*)(src + n * CCH + g * 8);
    *(bf16x8*)&os[n * XS_S + g * 8] = v;
  }
  __syncthreads();
  int b = wb >> 10, rem = wb & 1023;
  int wd = rem >> 6, wh = (rem >> 3) & 7, ww = rem & 7;
  for (int job = wid; job < 42; job += 4) {
    int mt = job / 6, ct = job - (job / 6) * 6;
    float bv = pb[ct * 16 + lr];
    f32x4 acc = {bv, bv, bv, bv};
    const __hip_bfloat16* wrow = pwb + (size_t)(ct * 16 + lr) * CCH;
    #pragma unroll
    for (int ks = 0; ks < 3; ++ks) {
      bf16x8 a = *(const bf16x8*)&os[(mt * 16 + lr) * XS_S + ks * 32 + lq * 8];
      bf16x8 bw = *(const bf16x8*)(wrow + ks * 32 + lq * 8);
      acc = MFMA(a, bw, acc);
    }
    #pragma unroll
    for (int r = 0; r < 4; ++r) {
      int token = mt * 16 + lq * 4 + r;
      if (token < NT) {
        int id = token / 49, r2 = token - id * 49;
        int ih = r2 / 7, iw = r2 - ih * 7;
        int dd = wd * 2 + id + 1; if (dd >= 32) dd -= 32;
        int hh = wh * 7 + ih + 3; if (hh >= 56) hh -= 56;
        int w2 = ww * 7 + iw + 3; if (w2 >= 56) w2 -= 56;
        size_t gi = ((((size_t)b * 32 + dd) * 56 + hh) * 56 + w2) * CCH + ct * 16 + lr;
        out[gi] = x[gi] + acc[r];
      }
    }
  }
}

// ---------------- Kernel 4: MFMA MLP: LN2 + fc1 + GELU + fc2 + residual ---
// 32 tokens/block, LDS = Xb 6.5KB + Ht 24KB = 31.2KB -> 5 blocks/CU.
// fc1 TRANSPOSED (operand-swapped) -> packed b64 swizzled Ht stores;
// fc2 reads b128 with same swizzle. GELU via sigmoid approx.
#define XB_S 104
__global__ __launch_bounds__(256, 5) void k4_mlp(
    float* __restrict__ io, const float* __restrict__ g, const float* __restrict__ bt,
    const __hip_bfloat16* __restrict__ w1b, const float* __restrict__ b1,
    const __hip_bfloat16* __restrict__ w2b, const float* __restrict__ b2) {
  __shared__ __align__(16) __hip_bfloat16 Xb[32 * XB_S];   // 6656 B
  __shared__ __align__(16) __hip_bfloat16 Ht[32 * 384];    // 24576 B, swizzled
  int tid = threadIdx.x;
  size_t base = (size_t)blockIdx.x * 32 * CCH;
  {
    int grp = tid >> 5, lane = tid & 31;
    #pragma unroll
    for (int t0 = 0; t0 < 4; ++t0) {
      int t = grp + t0 * 8;
      const float* src = io + base + (size_t)t * CCH;
      float v0 = src[lane], v1 = src[lane + 32], v2 = src[lane + 64];
      float s = v0 + v1 + v2, ss = v0 * v0 + v1 * v1 + v2 * v2;
      #pragma unroll
      for (int off = 16; off; off >>= 1) {
        s  += __shfl_xor(s,  off, 32);
        ss += __shfl_xor(ss, off, 32);
      }
      float m   = s * (1.f / 96.f);
      float inv = rsqrtf(ss * (1.f / 96.f) - m * m + 1e-5f);
      Xb[t * XB_S + lane]      = __float2bfloat16((v0 - m) * inv * g[lane]      + bt[lane]);
      Xb[t * XB_S + lane + 32] = __float2bfloat16((v1 - m) * inv * g[lane + 32] + bt[lane + 32]);
      Xb[t * XB_S + lane + 64] = __float2bfloat16((v2 - m) * inv * g[lane + 64] + bt[lane + 64]);
    }
  }
  __syncthreads();
  int wid = tid >> 6, lane = tid & 63, lr = lane & 15, lq = lane >> 4;
  {
    bf16x8 xb[2][3];
    #pragma unroll
    for (int tt = 0; tt < 2; ++tt)
      #pragma unroll
      for (int ks = 0; ks < 3; ++ks)
        xb[tt][ks] = *(const bf16x8*)&Xb[(tt * 16 + lr) * XB_S + ks * 32 + lq * 8];
    f32x4 acc[2][6];
    #pragma unroll
    for (int nt = 0; nt < 6; ++nt) {
      f32x4 bv = *(const f32x4*)&b1[96 * wid + 16 * nt + 4 * lq];
      acc[0][nt] = bv;
      acc[1][nt] = bv;
    }
    const __hip_bfloat16* wrow = w1b + (size_t)(96 * wid + lr) * CCH;
    #pragma unroll
    for (int nt = 0; nt < 6; ++nt) {
      #pragma unroll
      for (int ks = 0; ks < 3; ++ks) {
        bf16x8 a = *(const bf16x8*)(wrow + (size_t)(16 * nt) * CCH + ks * 32 + lq * 8);
        acc[0][nt] = MFMA(a, xb[0][ks], acc[0][nt]);
        acc[1][nt] = MFMA(a, xb[1][ks], acc[1][nt]);
      }
    }
    #pragma unroll
    for (int tt = 0; tt < 2; ++tt) {
      int row = tt * 16 + lr;
      char* hb = (char*)Ht + row * 768;
      int sw = (row & 7) << 4;
      #pragma unroll
      for (int nt = 0; nt < 6; ++nt) {
        s16x4 pk;
        #pragma unroll
        for (int r = 0; r < 4; ++r) pk[r] = f2bf_s(gelu_f(acc[tt][nt][r]));
        *(s16x4*)(hb + ((192 * wid + 32 * nt + 8 * lq) ^ sw)) = pk;
      }
    }
  }
  __syncthreads();
  {
    int tt = wid >> 1, ntb = (wid & 1) * 3;
    f32x4 acc2[3];
    #pragma unroll
    for (int j = 0; j < 3; ++j) {
      float bv = b2[16 * (ntb + j) + lr];
      acc2[j] = {bv, bv, bv, bv};
    }
    const char* hb = (const char*)Ht + (tt * 16 + lr) * 768;
    int sw = (lr & 7) << 4;
    #pragma unroll 4
    for (int kk = 0; kk < 12; ++kk) {
      bf16x8 a = *(const bf16x8*)(hb + ((64 * kk + 16 * lq) ^ sw));
      #pragma unroll
      for (int j = 0; j < 3; ++j) {
        bf16x8 b = *(const bf16x8*)&w2b[(size_t)(16 * (ntb + j) + lr) * HID + kk * 32 + lq * 8];
        acc2[j] = MFMA(a, b, acc2[j]);
      }
    }
    #pragma unroll
    for (int j = 0; j < 3; ++j)
      #pragma unroll
      for (int r = 0; r < 4; ++r) {
        size_t gi = base + (size_t)(tt * 16 + lq * 4 + r) * CCH + 16 * (ntb + j) + lr;
        io[gi] = io[gi] + acc2[j][r];
      }
  }
}

extern "C" void kernel_launch(void* const* d_in, const int* in_sizes, int n_in,
                              void* d_out, int out_size, void* d_ws, size_t ws_size,
                              hipStream_t stream) {
  const float* x    = (const float*)d_in[0];
  const float* n1g  = (const float*)d_in[2];
  const float* n1b  = (const float*)d_in[3];
  const float* qkvw = (const float*)d_in[4];
  const float* qkvb = (const float*)d_in[5];
  const float* pw   = (const float*)d_in[6];
  const float* pb   = (const float*)d_in[7];
  const float* n2g  = (const float*)d_in[8];
  const float* n2b  = (const float*)d_in[9];
  const float* w1   = (const float*)d_in[10];
  const float* b1   = (const float*)d_in[11];
  const float* w2   = (const float*)d_in[12];
  const float* b2   = (const float*)d_in[13];
  float* out = (float*)d_out;

  __hip_bfloat16* xw    = (__hip_bfloat16*)d_ws;
  __hip_bfloat16* obuf  = xw + (size_t)NTOK * CCH;
  __hip_bfloat16* w1b   = obuf + (size_t)NTOK * CCH;
  __hip_bfloat16* w2b   = w1b + HID * CCH;
  __hip_bfloat16* qkvwb = w2b + HID * CCH;
  __hip_bfloat16* pwb   = qkvwb + 3 * CCH * CCH;

  k0_cvt<<<(HID * CCH + 255) / 256, 256, 0, stream>>>(w1, w2, qkvw, pw, w1b, w2b, qkvwb, pwb);
  k1_ln_window<<<NTOK / 8, 256, 0, stream>>>(x, n1g, n1b, xw);
  k2_attn<<<NWIN * 3, 256, 0, stream>>>(xw, qkvwb, qkvb, obuf);
  k3_proj<<<NWIN, 256, 0, stream>>>(obuf, x, pwb, pb, out);
  k4_mlp<<<NTOK / 32, 256, 0, stream>>>(out, n2g, n2b, w1b, b1, w2b, b2);
}

// Round 6
// 475.856 us; speedup vs baseline: 1.2919x; 1.0134x over previous
//
#include <hip/hip_runtime.h>
#include <hip/hip_bf16.h>

// Problem constants (B,D,H,W,C) = (2,32,56,56,96); WS=(2,7,7), SS=(1,3,3)
#define NTOK   200704      // B*D*H*W
#define NWIN   2048        // B * 1024 windows
#define NT     98          // tokens per window (2*7*7)
#define CCH    96
#define HID    384

typedef __attribute__((ext_vector_type(8))) short bf16x8;   // 8 bf16, 4 VGPRs
typedef __attribute__((ext_vector_type(4))) short s16x4;    // 4 bf16, 8 bytes
typedef __attribute__((ext_vector_type(4))) float f32x4;
typedef __attribute__((ext_vector_type(2))) float f32x2;
typedef __attribute__((ext_vector_type(4))) int   i32x4;

#define MFMA(a, b, c) __builtin_amdgcn_mfma_f32_16x16x32_bf16((a), (b), (c), 0, 0, 0)

__device__ __forceinline__ float bf2f(__hip_bfloat16 v) { return __bfloat162float(v); }

__device__ __forceinline__ short f2bf_s(float v) {
  __hip_bfloat16 h = __float2bfloat16(v);
  return *reinterpret_cast<short*>(&h);
}

__device__ __forceinline__ unsigned pack2(float a, float b) {
  unsigned ua = (unsigned short)f2bf_s(a);
  unsigned ub = (unsigned short)f2bf_s(b);
  return ua | (ub << 16);
}

// gelu(x) ~= x * sigmoid(1.5957691x + 0.0713548x^3)  (tanh-form GELU)
__device__ __forceinline__ float gelu_f(float v) {
  float u = v * (1.5957691216057308f + 0.0713548162726f * v * v);
  return __fdividef(v, 1.f + __expf(-u));
}

// ---------------- Kernel 0: convert weights to bf16 -----------------------
__global__ __launch_bounds__(256) void k0_cvt(
    const float* __restrict__ w1, const float* __restrict__ w2,
    const float* __restrict__ qkvw, const float* __restrict__ pw,
    __hip_bfloat16* __restrict__ w1b, __hip_bfloat16* __restrict__ w2b,
    __hip_bfloat16* __restrict__ qkvwb, __hip_bfloat16* __restrict__ pwb) {
  int i = blockIdx.x * 256 + threadIdx.x;
  if (i < HID * CCH) {
    w1b[i] = __float2bfloat16(w1[i]);
    w2b[i] = __float2bfloat16(w2[i]);
  }
  if (i < 3 * CCH * CCH) qkvwb[i] = __float2bfloat16(qkvw[i]);
  if (i < CCH * CCH)     pwb[i]   = __float2bfloat16(pw[i]);
}

// ---------------- Kernel 1: LN1 + shift + window partition -> xw (bf16) ----
__global__ __launch_bounds__(256) void k1_ln_window(
    const float* __restrict__ x, const float* __restrict__ g,
    const float* __restrict__ bt, __hip_bfloat16* __restrict__ xw) {
  int token = blockIdx.x * 8 + (threadIdx.x >> 5);
  int lane = threadIdx.x & 31;
  if (token >= NTOK) return;
  int wb = token / NT;
  int n  = token - wb * NT;
  int b = wb >> 10;
  int rem = wb & 1023;
  int wd = rem >> 6, wh = (rem >> 3) & 7, ww = rem & 7;
  int id = n / 49, ih = (n / 7) % 7, iw = n % 7;
  int dd = wd * 2 + id + 1; if (dd >= 32) dd -= 32;
  int hh = wh * 7 + ih + 3; if (hh >= 56) hh -= 56;
  int w2 = ww * 7 + iw + 3; if (w2 >= 56) w2 -= 56;
  const float* src = x + ((((size_t)b * 32 + dd) * 56 + hh) * 56 + w2) * CCH;
  float v0 = src[lane], v1 = src[lane + 32], v2 = src[lane + 64];
  float s = v0 + v1 + v2, ss = v0 * v0 + v1 * v1 + v2 * v2;
  #pragma unroll
  for (int off = 16; off; off >>= 1) {
    s  += __shfl_xor(s,  off, 32);
    ss += __shfl_xor(ss, off, 32);
  }
  float m   = s * (1.f / 96.f);
  float inv = rsqrtf(ss * (1.f / 96.f) - m * m + 1e-5f);
  __hip_bfloat16* dst = xw + (size_t)token * CCH;
  dst[lane]      = __float2bfloat16((v0 - m) * inv * g[lane]      + bt[lane]);
  dst[lane + 32] = __float2bfloat16((v1 - m) * inv * g[lane + 32] + bt[lane + 32]);
  dst[lane + 64] = __float2bfloat16((v2 - m) * inv * g[lane + 64] + bt[lane + 64]);
}

// ---------------- Kernel 2: per-(window,head) MFMA attention --------------
// No Xs staging, operand-swapped QKV/QK^T/PV, register P, arithmetic mask.
// LDS 25.7KB, 1 barrier. (validated Round 5)
#define QK_S 40     // Q/K row stride (elems)
#define VT_S 120    // V^T row stride (elems); cols 0..111 used
__global__ __launch_bounds__(256, 4) void k2_attn(
    const __hip_bfloat16* __restrict__ xw, const __hip_bfloat16* __restrict__ qkvwb,
    const float* __restrict__ qkv_b, __hip_bfloat16* __restrict__ obuf) {
  __shared__ __align__(16) __hip_bfloat16 Qs[112 * QK_S];   // [token][dim]
  __shared__ __align__(16) __hip_bfloat16 Ks[112 * QK_S];   // [token][dim]
  __shared__ __align__(16) __hip_bfloat16 Vts[32 * VT_S];   // [dim][token]
  __shared__ unsigned char ridL[112];
  int bid = blockIdx.x, tid = threadIdx.x;
  int wb = bid / 3, h = bid - wb * 3;
  int wid = tid >> 6, lane = tid & 63, lr = lane & 15, lq = lane >> 4;
  int mw = wb & 1023;
  int wd = mw >> 6, wh = (mw >> 3) & 7, ww = mw & 7;
  bool hasmask = (wd == 15) || (wh == 7) || (ww == 7);
  const __hip_bfloat16* xp = xw + (size_t)wb * (NT * CCH);
  int h32 = h * 32;

  if (tid < 112) {
    int n = tid < NT ? tid : NT - 1;
    int id = n / 49, r2 = n - id * 49, ih = r2 / 7, iw = r2 - ih * 7;
    int ud = wd * 2 + id, uh = wh * 7 + ih, uw = ww * 7 + iw;
    int dr = (ud < 30) ? 0 : (ud == 30 ? 1 : 2);
    int hr = (uh < 49) ? 0 : (uh < 53 ? 1 : 2);
    int wr = (uw < 49) ? 0 : (uw < 53 ? 1 : 2);
    ridL[tid] = (unsigned char)(dr * 9 + hr * 3 + wr);
  }

  // ---- QKV: 7 token-tiles x 6 out-tiles (Q0,Q1,K0,K1,V0,V1), K=96 ----
  for (int job = wid; job < 42; job += 4) {
    int mt = job / 6, ct = job - (job / 6) * 6;
    int tok = mt * 16 + lr;
    int tokc = tok < NT ? tok : NT - 1;       // clamp: rows >=98 duplicate 97
    const __hip_bfloat16* xrow = xp + (size_t)tokc * CCH;
    bf16x8 xf0 = *(const bf16x8*)(xrow + lq * 8);
    bf16x8 xf1 = *(const bf16x8*)(xrow + 32 + lq * 8);
    bf16x8 xf2 = *(const bf16x8*)(xrow + 64 + lq * 8);
    if (ct < 4) {
      int which = ct >> 1;                    // 0=Q, 1=K
      int grow0 = which * CCH + h32 + (ct & 1) * 16;
      const __hip_bfloat16* wr0 = qkvwb + (size_t)(grow0 + lr) * CCH;
      f32x4 acc = *(const f32x4*)&qkv_b[grow0 + lq * 4];
      acc = MFMA(*(const bf16x8*)(wr0 + lq * 8),      xf0, acc);
      acc = MFMA(*(const bf16x8*)(wr0 + 32 + lq * 8), xf1, acc);
      acc = MFMA(*(const bf16x8*)(wr0 + 64 + lq * 8), xf2, acc);
      if (which == 0) {
        #pragma unroll
        for (int r = 0; r < 4; ++r) acc[r] *= 0.17677669529663689f;
      }
      s16x4 pk4;
      #pragma unroll
      for (int r = 0; r < 4; ++r) pk4[r] = f2bf_s(acc[r]);
      __hip_bfloat16* dst = (which == 0) ? Qs : Ks;
      *(s16x4*)&dst[tok * QK_S + (ct & 1) * 16 + lq * 4] = pk4;
    } else {
      int dt = ct & 1;
      int vrow = 2 * CCH + h32 + dt * 16 + lr;
      const __hip_bfloat16* wv = qkvwb + (size_t)vrow * CCH;
      float bv = qkv_b[vrow];
      f32x4 acc = {bv, bv, bv, bv};
      acc = MFMA(xf0, *(const bf16x8*)(wv + lq * 8),      acc);
      acc = MFMA(xf1, *(const bf16x8*)(wv + 32 + lq * 8), acc);
      acc = MFMA(xf2, *(const bf16x8*)(wv + 64 + lq * 8), acc);
      s16x4 pk4;
      #pragma unroll
      for (int r = 0; r < 4; ++r) pk4[r] = f2bf_s(acc[r]);
      *(s16x4*)&Vts[(dt * 16 + lr) * VT_S + mt * 16 + lq * 4] = pk4;
    }
  }
  __syncthreads();

  // ---- attention: S^T = K*Q^T; softmax per lane (query=lr); O^T = V^T*P^T
  for (int mt = wid; mt < 7; mt += 4) {
    bf16x8 qf = *(const bf16x8*)&Qs[(mt * 16 + lr) * QK_S + lq * 8];
    f32x4 s[7];
    #pragma unroll
    for (int nt = 0; nt < 7; ++nt) s[nt] = {0.f, 0.f, 0.f, 0.f};
    #pragma unroll
    for (int nt = 0; nt < 7; ++nt) {
      bf16x8 kf = *(const bf16x8*)&Ks[(nt * 16 + lr) * QK_S + lq * 8];
      s[nt] = MFMA(kf, qf, s[nt]);   // lane: key = nt*16+lq*4+r, query = mt*16+lr
    }
    if (hasmask) {
      int rq = ridL[mt * 16 + lr];
      #pragma unroll
      for (int nt = 0; nt < 7; ++nt)
        #pragma unroll
        for (int r = 0; r < 4; ++r)
          s[nt][r] += (ridL[nt * 16 + lq * 4 + r] != rq) ? -100.f : 0.f;
    }
    #pragma unroll
    for (int r = 0; r < 4; ++r)   // kill keys 98..111
      s[6][r] = (lq * 4 + r >= 2) ? -1e30f : s[6][r];
    float m = s[0][0];
    #pragma unroll
    for (int nt = 0; nt < 7; ++nt)
      #pragma unroll
      for (int r = 0; r < 4; ++r) m = fmaxf(m, s[nt][r]);
    m = fmaxf(m, __shfl_xor(m, 16));
    m = fmaxf(m, __shfl_xor(m, 32));
    float sum = 0.f;
    #pragma unroll
    for (int nt = 0; nt < 7; ++nt)
      #pragma unroll
      for (int r = 0; r < 4; ++r) {
        float e = __expf(s[nt][r] - m);
        s[nt][r] = e;
        sum += e;
      }
    sum += __shfl_xor(sum, 16);
    sum += __shfl_xor(sum, 32);
    float inv = 1.f / sum;
    #pragma unroll
    for (int nt = 0; nt < 7; ++nt)
      #pragma unroll
      for (int r = 0; r < 4; ++r) s[nt][r] *= inv;
    unsigned pk[6][2];
    #pragma unroll
    for (int nt = 0; nt < 6; ++nt) {
      pk[nt][0] = pack2(s[nt][0], s[nt][1]);
      pk[nt][1] = pack2(s[nt][2], s[nt][3]);
    }
    // PV: build P^T b-frags via shfl (elem j lane l = P[q=lr][ks*32+lq*8+j])
    f32x4 o0 = {0.f, 0.f, 0.f, 0.f}, o1 = {0.f, 0.f, 0.f, 0.f};
    int srcA = lr + ((lq & 1) << 5);
    bool hi = (lq & 2) != 0;
    #pragma unroll
    for (int ks = 0; ks < 3; ++ks) {
      int a0 = __shfl((int)pk[2 * ks][0], srcA);
      int b0 = __shfl((int)pk[2 * ks + 1][0], srcA);
      int a1 = __shfl((int)pk[2 * ks][1], srcA);
      int b1 = __shfl((int)pk[2 * ks + 1][1], srcA);
      int a2 = __shfl((int)pk[2 * ks][0], srcA + 16);
      int b2 = __shfl((int)pk[2 * ks + 1][0], srcA + 16);
      int a3 = __shfl((int)pk[2 * ks][1], srcA + 16);
      int b3 = __shfl((int)pk[2 * ks + 1][1], srcA + 16);
      i32x4 wv4;
      wv4[0] = hi ? b0 : a0;
      wv4[1] = hi ? b1 : a1;
      wv4[2] = hi ? b2 : a2;
      wv4[3] = hi ? b3 : a3;
      bf16x8 pf = __builtin_bit_cast(bf16x8, wv4);
      o0 = MFMA(*(const bf16x8*)&Vts[lr * VT_S + ks * 32 + lq * 8], pf, o0);
      o1 = MFMA(*(const bf16x8*)&Vts[(16 + lr) * VT_S + ks * 32 + lq * 8], pf, o1);
    }
    float p96 = __shfl(s[6][0], lr);
    float p97 = __shfl(s[6][1], lr);
    #pragma unroll
    for (int r = 0; r < 4; ++r) {
      int d0 = lq * 4 + r, d1 = 16 + lq * 4 + r;
      o0[r] += p96 * bf2f(Vts[d0 * VT_S + 96]) + p97 * bf2f(Vts[d0 * VT_S + 97]);
      o1[r] += p96 * bf2f(Vts[d1 * VT_S + 96]) + p97 * bf2f(Vts[d1 * VT_S + 97]);
    }
    int q = mt * 16 + lr;
    if (q < NT) {
      __hip_bfloat16* ob = obuf + ((size_t)wb * NT + q) * CCH + h32;
      s16x4 w0, w1;
      #pragma unroll
      for (int r = 0; r < 4; ++r) { w0[r] = f2bf_s(o0[r]); w1[r] = f2bf_s(o1[r]); }
      *(s16x4*)(ob + lq * 4) = w0;
      *(s16x4*)(ob + 16 + lq * 4) = w1;
    }
  }
}

// ---------------- Kernel 3: MFMA proj + window-reverse + residual ---------
// Operand-swapped proj (D = Wp * os^T): lane holds ONE token (mt*16+lr) and
// 4 consecutive channels (ct*16+lq*4..+3) -> window-reverse address computed
// once per job, residual RMW is one f32x4 load + one f32x4 store.
#define XS_S 104
__global__ __launch_bounds__(256) void k3_proj(
    const __hip_bfloat16* __restrict__ obuf, const float* __restrict__ x,
    const __hip_bfloat16* __restrict__ pwb, const float* __restrict__ pb,
    float* __restrict__ out) {
  __shared__ __align__(16) __hip_bfloat16 os[112 * XS_S];
  int wb = blockIdx.x, tid = threadIdx.x;
  int wid = tid >> 6, lane = tid & 63, lr = lane & 15, lq = lane >> 4;
  const __hip_bfloat16* src = obuf + (size_t)wb * (NT * CCH);
  for (int q = tid; q < 112 * 12; q += 256) {
    int n = q / 12, g = q - n * 12;
    bf16x8 v = {0, 0, 0, 0, 0, 0, 0, 0};
    if (n < NT) v = *(const bf16x8*)(src + n * CCH + g * 8);
    *(bf16x8*)&os[n * XS_S + g * 8] = v;
  }
  __syncthreads();
  int b = wb >> 10, rem = wb & 1023;
  int wd = rem >> 6, wh = (rem >> 3) & 7, ww = rem & 7;
  for (int job = wid; job < 42; job += 4) {
    int mt = job / 6, ct = job - (job / 6) * 6;
    f32x4 acc = *(const f32x4*)&pb[ct * 16 + lq * 4];
    const __hip_bfloat16* wrow = pwb + (size_t)(ct * 16 + lr) * CCH;
    #pragma unroll
    for (int ks = 0; ks < 3; ++ks) {
      bf16x8 osf = *(const bf16x8*)&os[(mt * 16 + lr) * XS_S + ks * 32 + lq * 8];
      bf16x8 wf  = *(const bf16x8*)(wrow + ks * 32 + lq * 8);
      acc = MFMA(wf, osf, acc);   // D: col=token(lr), row=ch(lq*4+r)
    }
    int token = mt * 16 + lr;
    if (token < NT) {
      int id = token / 49, r2 = token - id * 49;
      int ih = r2 / 7, iw = r2 - ih * 7;
      int dd = wd * 2 + id + 1; if (dd >= 32) dd -= 32;
      int hh = wh * 7 + ih + 3; if (hh >= 56) hh -= 56;
      int w2 = ww * 7 + iw + 3; if (w2 >= 56) w2 -= 56;
      size_t gi = ((((size_t)b * 32 + dd) * 56 + hh) * 56 + w2) * CCH + ct * 16 + lq * 4;
      f32x4 xv = *(const f32x4*)&x[gi];
      *(f32x4*)&out[gi] = xv + acc;
    }
  }
}

// ---------------- Kernel 4: MFMA MLP: LN2 + fc1 + GELU + fc2 + residual ---
// 32 tokens/block, LDS = Xb 6.5KB + Ht 24KB = 31.2KB -> 5 blocks/CU.
// LN: 16 lanes/token, f32x4+f32x2 loads, 4-step butterfly (was 10 shfls).
// fc1 TRANSPOSED -> packed b64 swizzled Ht stores. fc2 SWAPPED (D = W2*H^T):
// identical LDS/weight reads, but lane holds one token x 4 consecutive chs
// -> residual RMW is 3 dwordx4 loads + 3 dwordx4 stores (was 12+12 scalar).
#define XB_S 104
__global__ __launch_bounds__(256, 5) void k4_mlp(
    float* __restrict__ io, const float* __restrict__ g, const float* __restrict__ bt,
    const __hip_bfloat16* __restrict__ w1b, const float* __restrict__ b1,
    const __hip_bfloat16* __restrict__ w2b, const float* __restrict__ b2) {
  __shared__ __align__(16) __hip_bfloat16 Xb[32 * XB_S];   // 6656 B
  __shared__ __align__(16) __hip_bfloat16 Ht[32 * 384];    // 24576 B, swizzled
  int tid = threadIdx.x;
  size_t base = (size_t)blockIdx.x * 32 * CCH;
  {
    int lsub = tid & 15;
    int tg = tid >> 4;                       // 0..15
    f32x4 gv  = *(const f32x4*)&g[lsub * 4];
    f32x4 btv = *(const f32x4*)&bt[lsub * 4];
    f32x2 g2  = *(const f32x2*)&g[64 + lsub * 2];
    f32x2 bt2 = *(const f32x2*)&bt[64 + lsub * 2];
    #pragma unroll
    for (int it = 0; it < 2; ++it) {
      int t = tg + it * 16;
      const float* src = io + base + (size_t)t * CCH;
      f32x4 a  = *(const f32x4*)(src + lsub * 4);
      f32x2 b2v = *(const f32x2*)(src + 64 + lsub * 2);
      float s  = a[0] + a[1] + a[2] + a[3] + b2v[0] + b2v[1];
      float ss = a[0]*a[0] + a[1]*a[1] + a[2]*a[2] + a[3]*a[3]
               + b2v[0]*b2v[0] + b2v[1]*b2v[1];
      #pragma unroll
      for (int off = 1; off < 16; off <<= 1) {
        s  += __shfl_xor(s,  off);
        ss += __shfl_xor(ss, off);
      }
      float m   = s * (1.f / 96.f);
      float inv = rsqrtf(ss * (1.f / 96.f) - m * m + 1e-5f);
      s16x4 pk4;
      #pragma unroll
      for (int r = 0; r < 4; ++r)
        pk4[r] = f2bf_s((a[r] - m) * inv * gv[r] + btv[r]);
      *(s16x4*)&Xb[t * XB_S + lsub * 4] = pk4;
      unsigned p2 = pack2((b2v[0] - m) * inv * g2[0] + bt2[0],
                          (b2v[1] - m) * inv * g2[1] + bt2[1]);
      *(unsigned*)&Xb[t * XB_S + 64 + lsub * 2] = p2;
    }
  }
  __syncthreads();
  int wid = tid >> 6, lane = tid & 63, lr = lane & 15, lq = lane >> 4;
  // ---- fc1' (transposed): lane holds token=lr, 4 consecutive hid values
  {
    bf16x8 xb[2][3];
    #pragma unroll
    for (int tt = 0; tt < 2; ++tt)
      #pragma unroll
      for (int ks = 0; ks < 3; ++ks)
        xb[tt][ks] = *(const bf16x8*)&Xb[(tt * 16 + lr) * XB_S + ks * 32 + lq * 8];
    f32x4 acc[2][6];
    #pragma unroll
    for (int nt = 0; nt < 6; ++nt) {
      f32x4 bv = *(const f32x4*)&b1[96 * wid + 16 * nt + 4 * lq];
      acc[0][nt] = bv;
      acc[1][nt] = bv;
    }
    const __hip_bfloat16* wrow = w1b + (size_t)(96 * wid + lr) * CCH;
    #pragma unroll
    for (int nt = 0; nt < 6; ++nt) {
      #pragma unroll
      for (int ks = 0; ks < 3; ++ks) {
        bf16x8 a = *(const bf16x8*)(wrow + (size_t)(16 * nt) * CCH + ks * 32 + lq * 8);
        acc[0][nt] = MFMA(a, xb[0][ks], acc[0][nt]);
        acc[1][nt] = MFMA(a, xb[1][ks], acc[1][nt]);
      }
    }
    #pragma unroll
    for (int tt = 0; tt < 2; ++tt) {
      int row = tt * 16 + lr;
      char* hb = (char*)Ht + row * 768;
      int sw = (row & 7) << 4;
      #pragma unroll
      for (int nt = 0; nt < 6; ++nt) {
        s16x4 pk;
        #pragma unroll
        for (int r = 0; r < 4; ++r) pk[r] = f2bf_s(gelu_f(acc[tt][nt][r]));
        *(s16x4*)(hb + ((192 * wid + 32 * nt + 8 * lq) ^ sw)) = pk;
      }
    }
  }
  __syncthreads();
  // ---- fc2 SWAPPED: D = W2 * H^T -> lane: token tt*16+lr, chs 16*nt+lq*4..
  {
    int tt = wid >> 1, ntb = (wid & 1) * 3;
    f32x4 acc2[3];
    #pragma unroll
    for (int j = 0; j < 3; ++j)
      acc2[j] = *(const f32x4*)&b2[16 * (ntb + j) + lq * 4];
    const char* hb = (const char*)Ht + (tt * 16 + lr) * 768;
    int sw = (lr & 7) << 4;
    #pragma unroll 4
    for (int kk = 0; kk < 12; ++kk) {
      bf16x8 hfr = *(const bf16x8*)(hb + ((64 * kk + 16 * lq) ^ sw));
      #pragma unroll
      for (int j = 0; j < 3; ++j) {
        bf16x8 wfr = *(const bf16x8*)&w2b[(size_t)(16 * (ntb + j) + lr) * HID + kk * 32 + lq * 8];
        acc2[j] = MFMA(wfr, hfr, acc2[j]);
      }
    }
    int token = tt * 16 + lr;
    float* orow = io + base + (size_t)token * CCH;
    #pragma unroll
    for (int j = 0; j < 3; ++j) {
      int ch0 = 16 * (ntb + j) + lq * 4;
      f32x4 cur = *(const f32x4*)(orow + ch0);
      *(f32x4*)(orow + ch0) = cur + acc2[j];
    }
  }
}

extern "C" void kernel_launch(void* const* d_in, const int* in_sizes, int n_in,
                              void* d_out, int out_size, void* d_ws, size_t ws_size,
                              hipStream_t stream) {
  const float* x    = (const float*)d_in[0];
  const float* n1g  = (const float*)d_in[2];
  const float* n1b  = (const float*)d_in[3];
  const float* qkvw = (const float*)d_in[4];
  const float* qkvb = (const float*)d_in[5];
  const float* pw   = (const float*)d_in[6];
  const float* pb   = (const float*)d_in[7];
  const float* n2g  = (const float*)d_in[8];
  const float* n2b  = (const float*)d_in[9];
  const float* w1   = (const float*)d_in[10];
  const float* b1   = (const float*)d_in[11];
  const float* w2   = (const float*)d_in[12];
  const float* b2   = (const float*)d_in[13];
  float* out = (float*)d_out;

  __hip_bfloat16* xw    = (__hip_bfloat16*)d_ws;
  __hip_bfloat16* obuf  = xw + (size_t)NTOK * CCH;
  __hip_bfloat16* w1b   = obuf + (size_t)NTOK * CCH;
  __hip_bfloat16* w2b   = w1b + HID * CCH;
  __hip_bfloat16* qkvwb = w2b + HID * CCH;
  __hip_bfloat16* pwb   = qkvwb + 3 * CCH * CCH;

  k0_cvt<<<(HID * CCH + 255) / 256, 256, 0, stream>>>(w1, w2, qkvw, pw, w1b, w2b, qkvwb, pwb);
  k1_ln_window<<<NTOK / 8, 256, 0, stream>>>(x, n1g, n1b, xw);
  k2_attn<<<NWIN * 3, 256, 0, stream>>>(xw, qkvwb, qkvb, obuf);
  k3_proj<<<NWIN, 256, 0, stream>>>(obuf, x, pwb, pb, out);
  k4_mlp<<<NTOK / 32, 256, 0, stream>>>(out, n2g, n2b, w1b, b1, w2b, b2);
}